// Round 5
// baseline (27.915 us; speedup 1.0000x reference)
//
#include <hip/hip_runtime.h>

typedef float v2f __attribute__((ext_vector_type(2)));

#define N 512
#define P 2
#define DX 128
#define K 127
#define CLAMP_C 1e-4f
#define LOG2E_C 1.4426950408889634f
#define LN2_C 0.6931471805599453f
#define LOG2PI_C 1.8378770664093453f

#define JT 8                 // j-values per block
#define OUTS 16              // JT*P accumulators
#define NPAIR 8              // OUTS/2 float2 pairs (pair = {dz0, dz1} of one j)
#define ICH 32               // i-rows per chunk
#define NCHUNK 16            // N/ICH

#define WS_PART 0            // NCHUNK * N * P floats

// raw gfx950 transcendental ops (base-2)
#define EXP2F(v) __builtin_amdgcn_exp2f(v)
#define LOG2F(v) __builtin_amdgcn_logf(v)

__device__ __forceinline__ v2f splat2(float a) { v2f r; r.x = a; r.y = a; return r; }

__global__ __launch_bounds__(256, 4)
void fused_kernel(const float* __restrict__ z, const float* __restrict__ x,
                  const float* __restrict__ theta, float* __restrict__ ws) {
    __shared__ float xs[ICH * 129];            // padded rows
    const int jt = blockIdx.x >> 4;            // 0..63 (j tile)
    const int c  = blockIdx.x & 15;            // 0..15 (i chunk)
    const int j0 = jt * JT;
    const int i0 = c * ICH;
    const int tid  = threadIdx.x;
    const int k    = tid & 127;
    const int half = tid >> 7;
    const int ke   = (k < K) ? k : (K - 1);
    const bool valid = (k < K);

    // stage 1: coalesced float4 load of this chunk's 32 rows into padded LDS
    const float4* xg = (const float4*)(x + i0 * DX);
    #pragma unroll
    for (int t = tid; t < ICH * 32; t += 256) {
        const int r = t >> 5, c4 = t & 31;
        const float4 v = xg[t];
        float* dst = xs + r * 129 + c4 * 4;
        dst[0] = v.x; dst[1] = v.y; dst[2] = v.z; dst[3] = v.w;
    }
    __syncthreads();

    // stage 2: in-place decayed scan (32 threads); banks (r+kk)%32 -> conflict-free
    if (tid < ICH) {
        float* row = xs + tid * 129;
        float dacc = 0.f;
        float xk = row[0];
        #pragma unroll 1
        for (int kk = 0; kk < K; ++kk) {
            dacc = (dacc + xk) * 0.1f;                 // d[i,kk]
            const float xk1 = row[kk + 1];
            const float ed = EXP2F(-dacc * LOG2E_C);   // exp(-d) in (0.89, 1]
            row[kk] = (xk1 != 0.f) ? -ed : ed;         // pack x[i,kk+1] into sign
            xk = xk1;
        }
        row[K] = 1.0f;                                 // pad (masked by `valid`)
    }

    // eu (independent of xs) — overlaps the scan for non-scan threads
    const float th0 = theta[ke + 1] * LOG2E_C;         // base-2 fold
    const float th1 = theta[DX + ke + 1] * LOG2E_C;
    v2f eu[NPAIR];
    #pragma unroll
    for (int q = 0; q < NPAIR; ++q) {                  // pair q = j0+q; {dz0, dz1}
        const float* zq = z + (j0 + q) * 4;
        eu[q].x = EXP2F(-(zq[0] * th0 + zq[1] * th1));
        eu[q].y = EXP2F(-(zq[2] * th0 + zq[3] * th1));
    }
    __syncthreads();

    v2f acc[NPAIR];
    #pragma unroll
    for (int q = 0; q < NPAIR; ++q) acc[q] = splat2(0.f);

    const float* rowp = xs + (half * 16) * 129 + ke;

    // 2 batches of 8 rows; f32 range safe: den <= ~(1+e)^8, num >= 1e-32
    #pragma unroll
    for (int hb = 0; hb < 2; ++hb) {
        v2f num[NPAIR], den[NPAIR];
        #pragma unroll
        for (int q = 0; q < NPAIR; ++q) { num[q] = splat2(1.f); den[q] = splat2(1.f); }
        #pragma unroll
        for (int hh = 0; hh < 8; ++hh) {
            const float eds = rowp[(hb * 8 + hh) * 129];
            const float xv1 = (eds < 0.f) ? 1.f : 0.f;             // x[i,k+1]
            const float ca  = fmaf(xv1, -(1.f + 2.f * CLAMP_C), 1.f + CLAMP_C);
            const float cb  = fmaf(xv1, 1.f - 2.f * CLAMP_C, CLAMP_C);
            const float ed  = __builtin_fabsf(eds);
            const v2f ed2 = splat2(ed), ca2 = splat2(ca), cb2 = splat2(cb);
            #pragma unroll
            for (int q = 0; q < NPAIR; ++q) {
                const v2f e2 = ed2 * eu[q];            // exp(-(d+u)), packed
                den[q] = den[q] * e2 + den[q];         // *= (1+e)  (pk_fma)
                num[q] = num[q] * (ca2 * e2 + cb2);    // *= clamped numerator
            }
        }
        #pragma unroll
        for (int q = 0; q < NPAIR; ++q) {
            acc[q].x += LOG2F(num[q].x) - LOG2F(den[q].x);
            acc[q].y += LOG2F(num[q].y) - LOG2F(den[q].y);
        }
    }

    // single-barrier block reduction of 16 accumulators
    __shared__ float red[4][OUTS];
    #pragma unroll
    for (int q = 0; q < NPAIR; ++q) {
        float vx = valid ? acc[q].x : 0.f;
        float vy = valid ? acc[q].y : 0.f;
        #pragma unroll
        for (int off = 32; off > 0; off >>= 1) {
            vx += __shfl_down(vx, off, 64);
            vy += __shfl_down(vy, off, 64);
        }
        if ((tid & 63) == 0) { red[tid >> 6][2 * q] = vx; red[tid >> 6][2 * q + 1] = vy; }
    }
    __syncthreads();
    if (tid < OUTS) {
        const float t = (red[0][tid] + red[1][tid] + red[2][tid] + red[3][tid]) * LN2_C;
        const int jj = tid >> 1, dz = tid & 1;
        ws[WS_PART + c * (N * P) + (j0 + jj) * P + dz] = t;
    }
}

__global__ __launch_bounds__(256)
void final_kernel(const float* __restrict__ z, const float* __restrict__ x,
                  const float* __restrict__ theta, const float* __restrict__ ws,
                  float* __restrict__ out) {
    // redundant per-block S0 = sum_i x[i,0] (512 L2-hit loads, exact)
    __shared__ float red[256];
    const int tid = threadIdx.x;
    red[tid] = x[tid * DX] + x[(tid + 256) * DX];
    __syncthreads();
    for (int s = 128; s > 0; s >>= 1) {
        if (tid < s) red[tid] += red[tid + s];
        __syncthreads();
    }
    const float S0 = red[0];

    const int gid = blockIdx.x * 256 + tid;    // grid 4*256 = N*P exactly
    const int j = gid >> 1, dz = gid & 1;
    const float z0 = z[j * 4 + dz * 2];
    const float z1 = z[j * 4 + dz * 2 + 1];

    // lp = logpdf(z0, 1e-3) + logpdf(z1, exp(z0/4)); log(exp(z0/4)) == z0/4
    const float t1 = z0 * 1000.f;
    const float e4 = __expf(-z0 * 0.25f);
    const float t2 = z1 * e4;
    const float lp = -0.5f * t1 * t1 + 6.9077552790f   // -log(1e-3)
                   - 0.5f * t2 * t2 - z0 * 0.25f - LOG2PI_C;

    // lp0
    const float up0 = z0 * theta[0] + z1 * theta[DX];
    const float p0  = 1.f / (1.f + __expf(-up0));
    const float lp0 = __logf(p0 - CLAMP_C) * S0
                    + __logf(1.f - p0 + CLAMP_C) * ((float)N - S0);

    float sum = 0.f;
    #pragma unroll
    for (int cc = 0; cc < NCHUNK; ++cc) sum += ws[WS_PART + cc * (N * P) + gid];
    out[gid] = lp + lp0 + sum;
}

extern "C" void kernel_launch(void* const* d_in, const int* in_sizes, int n_in,
                              void* d_out, int out_size, void* d_ws, size_t ws_size,
                              hipStream_t stream) {
    const float* z     = (const float*)d_in[0];   // (512, 2, 2)
    const float* x     = (const float*)d_in[1];   // (512, 128)
    const float* theta = (const float*)d_in[2];   // (2, 128)
    float* ws  = (float*)d_ws;
    float* out = (float*)d_out;                   // (512, 2) float32

    hipLaunchKernelGGL(fused_kernel, dim3((N / JT) * NCHUNK), dim3(256), 0, stream,
                       z, x, theta, ws);
    hipLaunchKernelGGL(final_kernel, dim3(4), dim3(256), 0, stream,
                       z, x, theta, ws, out);
}

// Round 6
// 22.976 us; speedup vs baseline: 1.2150x; 1.2150x over previous
//
#include <hip/hip_runtime.h>

typedef float v2f __attribute__((ext_vector_type(2)));

#define N 512
#define P 2
#define DX 128
#define CLAMP_C 1e-4f
#define LOG2E_C 1.4426950408889634f
#define LN2_C 0.6931471805599453f
#define LOG2PI_C 1.8378770664093453f

#define NQ 8                 // j-values per block (16 outputs)
#define ICH 32               // i-rows per chunk
#define NCHUNK 16            // N/ICH

// ws float offsets
#define WS_EDX  0            // 65536: sign(x[i,k+1]) packed on exp(-d[i,k]), [i][k]
#define WS_EU   65536        // 131072: exp(-u[j,dz,k]), [(j*2+dz)][k]
#define WS_PART 196608       // NCHUNK*N*P partials

#define EXP2F(v) __builtin_amdgcn_exp2f(v)

__device__ __forceinline__ v2f splat2(float a) { v2f r; r.x = a; r.y = a; return r; }

// log2(m) for m in [1,2): deg-5 Taylor @1.5, |err| <= ~4.6e-4 (budget ~1e5)
__device__ __forceinline__ v2f log2v(v2f m) {
    const v2f t = m - splat2(1.5f);
    v2f p = t * splat2(0.03799691f) + splat2(-0.07124420f);
    p = p * t + splat2(0.14248840f);
    p = p * t + splat2(-0.32059890f);
    p = p * t + splat2(0.96179669f);
    p = p * t + splat2(0.58496250f);
    return p;
}

// strip exponent into integer accumulator, renormalize mantissa to [1,2)
__device__ __forceinline__ float strip_add(float v, int& acc) {
    const unsigned b = __float_as_uint(v);
    acc += (int)(b >> 23);
    return __uint_as_float((b & 0x007fffffu) | 0x3f800000u);
}
__device__ __forceinline__ float strip_sub(float v, int& acc) {
    const unsigned b = __float_as_uint(v);
    acc -= (int)(b >> 23);
    return __uint_as_float((b & 0x007fffffu) | 0x3f800000u);
}

// one thread per table entry: edx (65536) then eu (131072); fully parallel FIR scan
__global__ __launch_bounds__(256)
void prep_kernel(const float* __restrict__ z, const float* __restrict__ x,
                 const float* __restrict__ theta, float* __restrict__ ws) {
    const int gid = blockIdx.x * 256 + threadIdx.x;
    if (gid < 65536) {
        const int i = gid >> 7, k = gid & 127;
        const float* xr = x + i * DX;
        // d[i,k] = sum_j 0.1^(j+1) x[i,k-j]; taps < 1e-7 dropped (tail err 1.1e-7)
        float d = 0.1f * xr[k];
        if (k >= 1) d = __builtin_fmaf(1e-2f, xr[k - 1], d);
        if (k >= 2) d = __builtin_fmaf(1e-3f, xr[k - 2], d);
        if (k >= 3) d = __builtin_fmaf(1e-4f, xr[k - 3], d);
        if (k >= 4) d = __builtin_fmaf(1e-5f, xr[k - 4], d);
        if (k >= 5) d = __builtin_fmaf(1e-6f, xr[k - 5], d);
        const float ed = EXP2F(-d * LOG2E_C);            // exp(-d) in (0.89, 1]
        const float xn = x[(gid + 1 < 65536) ? gid + 1 : 65535];
        ws[WS_EDX + gid] = (k < 127 && xn != 0.f) ? -ed : ed;  // k=127 pad, masked
    } else {
        const int t = gid - 65536;                       // [0, 131072)
        const int jd = t >> 7, k = t & 127;              // jd = j*2+dz
        const int kc = (k < 127) ? (k + 1) : 127;        // theta col k+1; pad clamped
        const float th0 = theta[kc] * LOG2E_C;
        const float th1 = theta[DX + kc] * LOG2E_C;
        const float z0 = z[jd * 2], z1 = z[jd * 2 + 1];
        ws[WS_EU + t] = EXP2F(-(z0 * th0 + z1 * th1));   // exp(-u)
    }
}

__global__ __launch_bounds__(256, 4)
void main_kernel(const float* __restrict__ edx, const float* __restrict__ eut,
                 float* __restrict__ part) {
    const int jt = blockIdx.x >> 4;            // 0..63
    const int c  = blockIdx.x & 15;            // 0..15
    const int j0 = jt * NQ;
    const int i0 = c * ICH;
    const int tid  = threadIdx.x;
    const int ke   = tid & 127;
    const int half = tid >> 7;
    const bool valid = (ke < 127);

    // eu fragments: v2f {dz=0, dz=1} per q, coalesced L2 loads
    const float* eub = eut + (j0 * 2) * 128 + ke;
    v2f eu[NQ];
    #pragma unroll
    for (int q = 0; q < NQ; ++q) {
        eu[q].x = eub[q * 256];
        eu[q].y = eub[q * 256 + 128];
    }

    const float* ep = edx + (i0 + half * 16) * 128 + ke;

    v2f num[NQ], den[NQ];
    int accX[NQ], accY[NQ];                    // sum of (num_exp - den_exp), biases cancel
    #pragma unroll
    for (int q = 0; q < NQ; ++q) {
        num[q] = splat2(1.f); den[q] = splat2(1.f);
        accX[q] = 0; accY[q] = 0;
    }

    #pragma unroll
    for (int hb = 0; hb < 2; ++hb) {
        #pragma unroll
        for (int hh = 0; hh < 8; ++hh) {
            const float eds = ep[(hb * 8 + hh) * 128];
            const bool  xb  = eds < 0.f;                       // x[i,k+1] == 1
            const float ca  = xb ? -CLAMP_C : (1.f + CLAMP_C);
            const float cb  = xb ? (1.f - CLAMP_C) : CLAMP_C;
            const v2f ed2 = splat2(__builtin_fabsf(eds));
            const v2f ca2 = splat2(ca), cb2 = splat2(cb);
            #pragma unroll
            for (int q = 0; q < NQ; ++q) {
                const v2f e2 = ed2 * eu[q];                    // exp(-(d+u))
                den[q] = den[q] * e2 + den[q];                 // *= (1+e)
                num[q] = num[q] * (ca2 * e2 + cb2);            // *= clamped numerator
            }
        }
        // strip exponents (no log!): int accumulate, renorm mantissa to [1,2)
        #pragma unroll
        for (int q = 0; q < NQ; ++q) {
            num[q].x = strip_add(num[q].x, accX[q]);
            num[q].y = strip_add(num[q].y, accY[q]);
            den[q].x = strip_sub(den[q].x, accX[q]);
            den[q].y = strip_sub(den[q].y, accY[q]);
        }
    }

    // finalize: log2 = accE + poly(m_num) - poly(m_den); reduce; store (ln units)
    __shared__ float red[4][16];
    #pragma unroll
    for (int q = 0; q < NQ; ++q) {
        const v2f pn = log2v(num[q]);
        const v2f pd = log2v(den[q]);
        float vx = valid ? ((float)accX[q] + pn.x - pd.x) : 0.f;
        float vy = valid ? ((float)accY[q] + pn.y - pd.y) : 0.f;
        #pragma unroll
        for (int off = 32; off > 0; off >>= 1) {
            vx += __shfl_xor(vx, off, 64);
            vy += __shfl_xor(vy, off, 64);
        }
        if ((tid & 63) == 0) { red[tid >> 6][2 * q] = vx; red[tid >> 6][2 * q + 1] = vy; }
    }
    __syncthreads();
    if (tid < 16) {
        const float t = (red[0][tid] + red[1][tid] + red[2][tid] + red[3][tid]) * LN2_C;
        part[c * (N * P) + (j0 + (tid >> 1)) * P + (tid & 1)] = t;
    }
}

__global__ __launch_bounds__(256)
void final_kernel(const float* __restrict__ z, const float* __restrict__ x,
                  const float* __restrict__ theta, const float* __restrict__ part,
                  float* __restrict__ out) {
    __shared__ float red[256];
    const int tid = threadIdx.x;
    red[tid] = x[tid * DX] + x[(tid + 256) * DX];
    __syncthreads();
    for (int s = 128; s > 0; s >>= 1) {
        if (tid < s) red[tid] += red[tid + s];
        __syncthreads();
    }
    const float S0 = red[0];

    const int gid = blockIdx.x * 256 + tid;    // grid 4*256 = N*P
    const int j = gid >> 1, dz = gid & 1;
    const float z0 = z[j * 4 + dz * 2];
    const float z1 = z[j * 4 + dz * 2 + 1];

    // lp = logpdf(z0, 1e-3) + logpdf(z1, exp(z0/4)); log(exp(z0/4)) == z0/4
    const float t1 = z0 * 1000.f;
    const float e4 = __expf(-z0 * 0.25f);
    const float t2 = z1 * e4;
    const float lp = -0.5f * t1 * t1 + 6.9077552790f   // -log(1e-3)
                   - 0.5f * t2 * t2 - z0 * 0.25f - LOG2PI_C;

    const float up0 = z0 * theta[0] + z1 * theta[DX];
    const float p0  = 1.f / (1.f + __expf(-up0));
    const float lp0 = __logf(p0 - CLAMP_C) * S0
                    + __logf(1.f - p0 + CLAMP_C) * ((float)N - S0);

    float sum = 0.f;
    #pragma unroll
    for (int cc = 0; cc < NCHUNK; ++cc) sum += part[cc * (N * P) + gid];
    out[gid] = lp + lp0 + sum;
}

extern "C" void kernel_launch(void* const* d_in, const int* in_sizes, int n_in,
                              void* d_out, int out_size, void* d_ws, size_t ws_size,
                              hipStream_t stream) {
    const float* z     = (const float*)d_in[0];   // (512, 2, 2)
    const float* x     = (const float*)d_in[1];   // (512, 128)
    const float* theta = (const float*)d_in[2];   // (2, 128)
    float* ws  = (float*)d_ws;
    float* out = (float*)d_out;                   // (512, 2) float32

    hipLaunchKernelGGL(prep_kernel,  dim3(768),  dim3(256), 0, stream, z, x, theta, ws);
    hipLaunchKernelGGL(main_kernel,  dim3(1024), dim3(256), 0, stream,
                       ws + WS_EDX, ws + WS_EU, ws + WS_PART);
    hipLaunchKernelGGL(final_kernel, dim3(4),    dim3(256), 0, stream,
                       z, x, theta, ws + WS_PART, out);
}